// Round 1
// baseline (40.438 us; speedup 1.0000x reference)
//
#include <hip/hip_runtime.h>
#include <cmath>

// Problem constants (fixed by the reference)
#define B_ 256
#define I_ 1024
#define O_ 1024

// GEMM tiling
#define BM 64
#define BN 64
#define BK 32
#define NSPLIT 4   // split-K factor -> grid 16*4*4 = 256 blocks

// ---------------------------------------------------------------------------
// Prep: lt[b,i] = log(tanh(100*|x[b,i]|)), clamped so 0*lt never makes NaN
// and exp(sum) correctly yields 0 when any masked factor is 0.
// ---------------------------------------------------------------------------
__global__ __launch_bounds__(256) void prep_lt(const float* __restrict__ x,
                                               float* __restrict__ lt) {
  int idx = (blockIdx.x * 256 + threadIdx.x) * 4;
  float4 xv = *reinterpret_cast<const float4*>(x + idx);
  float4 lv;
  lv.x = fmaxf(logf(tanhf(100.0f * fabsf(xv.x))), -1e30f);
  lv.y = fmaxf(logf(tanhf(100.0f * fabsf(xv.y))), -1e30f);
  lv.z = fmaxf(logf(tanhf(100.0f * fabsf(xv.z))), -1e30f);
  lv.w = fmaxf(logf(tanhf(100.0f * fabsf(xv.w))), -1e30f);
  *reinterpret_cast<float4*>(lt + idx) = lv;
}

// ---------------------------------------------------------------------------
// Dual GEMM: for the (bm,on) tile and k-chunk ks:
//   dot [b,o] += sum_k x [b,k] * (fc[o,k] * (vw[o,k]>0))
//   slog[b,o] += sum_k lt[b,k] * (vw[o,k]>0)
// SPLITK==1: apply epilogue directly. Else: write partials to workspace.
// ---------------------------------------------------------------------------
template <int SPLITK, bool USE_LT>
__global__ __launch_bounds__(256) void dual_gemm(
    const float* __restrict__ x, const float* __restrict__ vw,
    const float* __restrict__ fcw, const float* __restrict__ lt,
    float* __restrict__ out, float* __restrict__ pdot,
    float* __restrict__ pslog) {
  constexpr int KC = I_ / SPLITK;  // k-chunk length
  const int on0 = blockIdx.x * BN;
  const int bm0 = blockIdx.y * BM;
  const int k0 = blockIdx.z * KC;

  // [k][m] layout; +4 pad keeps float4 rows 16B-aligned (272B rows) and
  // reduces transposed-store conflicts from 32-way to 4-way.
  __shared__ float xs[BK][BM + 4];
  __shared__ float ls[BK][BM + 4];
  __shared__ float wsm[BK][BN + 4];
  __shared__ float msh[BK][BN + 4];

  const int t = threadIdx.x;          // 0..255
  const int tx = t & 15, ty = t >> 4; // 16x16 thread grid
  const int m0 = ty * 4, n0 = tx * 4; // 4x4 outputs per thread

  float accd[4][4] = {{0.f}};
  float accs[4][4] = {{0.f}};

  for (int kt = 0; kt < KC; kt += BK) {
    // Stage x/lt tile (64 rows x 32 k) and vw/fcw tile, coalesced in k.
#pragma unroll
    for (int j = 0; j < 8; ++j) {
      int f = j * 256 + t;     // 0..2047
      int m = f >> 5;          // row in tile (0..63)
      int kk = f & 31;         // k within tile
      int gk = k0 + kt + kk;
      float xv = x[(size_t)(bm0 + m) * I_ + gk];
      xs[kk][m] = xv;
      float lv;
      if constexpr (USE_LT) {
        lv = lt[(size_t)(bm0 + m) * I_ + gk];
      } else {
        lv = fmaxf(logf(tanhf(100.0f * fabsf(xv))), -1e30f);
      }
      ls[kk][m] = lv;
      float vv = vw[(size_t)(on0 + m) * I_ + gk];
      float fv = fcw[(size_t)(on0 + m) * I_ + gk];
      float mk = vv > 0.0f ? 1.0f : 0.0f;
      wsm[kk][m] = fv * mk;
      msh[kk][m] = mk;
    }
    __syncthreads();

#pragma unroll
    for (int kk = 0; kk < BK; ++kk) {
      float4 xv = *reinterpret_cast<const float4*>(&xs[kk][m0]);
      float4 lv = *reinterpret_cast<const float4*>(&ls[kk][m0]);
      float4 wv = *reinterpret_cast<const float4*>(&wsm[kk][n0]);
      float4 mv = *reinterpret_cast<const float4*>(&msh[kk][n0]);
      float xa[4] = {xv.x, xv.y, xv.z, xv.w};
      float la[4] = {lv.x, lv.y, lv.z, lv.w};
      float wa[4] = {wv.x, wv.y, wv.z, wv.w};
      float ma[4] = {mv.x, mv.y, mv.z, mv.w};
#pragma unroll
      for (int i = 0; i < 4; ++i) {
#pragma unroll
        for (int j = 0; j < 4; ++j) {
          accd[i][j] = fmaf(xa[i], wa[j], accd[i][j]);
          accs[i][j] = fmaf(la[i], ma[j], accs[i][j]);
        }
      }
    }
    __syncthreads();
  }

  if constexpr (SPLITK == 1) {
#pragma unroll
    for (int i = 0; i < 4; ++i) {
      int row = bm0 + m0 + i;
      float ys[4], ds[4];
#pragma unroll
      for (int j = 0; j < 4; ++j) {
        float delta = expf(accs[i][j]);
        ds[j] = delta;
        ys[j] = fmaxf(accd[i][j] * delta, 0.0f);
      }
      *reinterpret_cast<float4*>(&out[(size_t)row * O_ + on0 + n0]) =
          make_float4(ys[0], ys[1], ys[2], ys[3]);
      *reinterpret_cast<float4*>(&out[(size_t)B_ * O_ + (size_t)row * O_ + on0 + n0]) =
          make_float4(ds[0], ds[1], ds[2], ds[3]);
    }
  } else {
    const int ks = blockIdx.z;
#pragma unroll
    for (int i = 0; i < 4; ++i) {
      int row = bm0 + m0 + i;
      size_t base = (size_t)ks * B_ * O_ + (size_t)row * O_ + on0 + n0;
      *reinterpret_cast<float4*>(&pdot[base]) =
          make_float4(accd[i][0], accd[i][1], accd[i][2], accd[i][3]);
      *reinterpret_cast<float4*>(&pslog[base]) =
          make_float4(accs[i][0], accs[i][1], accs[i][2], accs[i][3]);
    }
  }
}

// ---------------------------------------------------------------------------
// Split-K reduction + epilogue: delta = exp(slog), y = relu(dot*delta)
// ---------------------------------------------------------------------------
__global__ __launch_bounds__(256) void reduce_ep(const float* __restrict__ pdot,
                                                 const float* __restrict__ pslog,
                                                 float* __restrict__ out) {
  int idx = blockIdx.x * 256 + threadIdx.x;  // 0 .. B*O-1
  float d = 0.f, s = 0.f;
#pragma unroll
  for (int ks = 0; ks < NSPLIT; ++ks) {
    d += pdot[(size_t)ks * B_ * O_ + idx];
    s += pslog[(size_t)ks * B_ * O_ + idx];
  }
  float delta = expf(s);
  out[idx] = fmaxf(d * delta, 0.0f);
  out[(size_t)B_ * O_ + idx] = delta;
}

extern "C" void kernel_launch(void* const* d_in, const int* in_sizes, int n_in,
                              void* d_out, int out_size, void* d_ws,
                              size_t ws_size, hipStream_t stream) {
  const float* x = (const float*)d_in[0];
  const float* vw = (const float*)d_in[1];
  const float* fcw = (const float*)d_in[2];
  float* out = (float*)d_out;

  const size_t ltBytes = (size_t)B_ * I_ * sizeof(float);            // 1 MB
  const size_t pBytes = (size_t)NSPLIT * B_ * O_ * sizeof(float);    // 4 MB

  float* lt = (float*)d_ws;
  float* pdot = (float*)((char*)d_ws + ltBytes);
  float* pslog = (float*)((char*)d_ws + ltBytes + pBytes);

  if (ws_size >= ltBytes + 2 * pBytes) {
    // Full path: prep + split-K dual GEMM (256 blocks) + reduce/epilogue.
    prep_lt<<<(B_ * I_) / 1024, 256, 0, stream>>>(x, lt);
    dual_gemm<NSPLIT, true>
        <<<dim3(O_ / BN, B_ / BM, NSPLIT), 256, 0, stream>>>(
            x, vw, fcw, lt, out, pdot, pslog);
    reduce_ep<<<(B_ * O_) / 256, 256, 0, stream>>>(pdot, pslog, out);
  } else if (ws_size >= ltBytes) {
    // No room for partials: single-chunk GEMM with fused epilogue.
    prep_lt<<<(B_ * I_) / 1024, 256, 0, stream>>>(x, lt);
    dual_gemm<1, true><<<dim3(O_ / BN, B_ / BM, 1), 256, 0, stream>>>(
        x, vw, fcw, lt, out, nullptr, nullptr);
  } else {
    // No usable workspace: recompute log(tanh) inline while staging.
    dual_gemm<1, false><<<dim3(O_ / BN, B_ / BM, 1), 256, 0, stream>>>(
        x, vw, fcw, nullptr, out, nullptr, nullptr);
  }
}

// Round 2
// 24.747 us; speedup vs baseline: 1.6341x; 1.6341x over previous
//
#include <hip/hip_runtime.h>
#include <cmath>

// Problem constants (fixed by the reference)
#define B_ 256
#define I_ 1024
#define O_ 1024
#define NSPLIT 4

typedef __attribute__((ext_vector_type(8))) short short8;   // 8 bf16 = 4 VGPRs
typedef __attribute__((ext_vector_type(4))) float f32x4;

// float -> bf16 bits, round-to-nearest-even (inputs are finite)
__device__ inline unsigned short f2bf(float f) {
  union { float f; unsigned u; } c;
  c.f = f;
  unsigned u = c.u;
  return (unsigned short)((u + 0x7FFFu + ((u >> 16) & 1u)) >> 16);
}

// ---------------------------------------------------------------------------
// Prep weights: wb = bf16(fc * (vw>0)), mb = bf16(vw>0). 8 elems/thread.
// ---------------------------------------------------------------------------
__global__ __launch_bounds__(256) void prep_w(const float* __restrict__ vw,
                                              const float* __restrict__ fcw,
                                              unsigned short* __restrict__ wb,
                                              unsigned short* __restrict__ mb) {
  int idx = (blockIdx.x * 256 + threadIdx.x) * 8;
  float4 v0 = *reinterpret_cast<const float4*>(vw + idx);
  float4 v1 = *reinterpret_cast<const float4*>(vw + idx + 4);
  float4 f0 = *reinterpret_cast<const float4*>(fcw + idx);
  float4 f1 = *reinterpret_cast<const float4*>(fcw + idx + 4);
  float va[8] = {v0.x, v0.y, v0.z, v0.w, v1.x, v1.y, v1.z, v1.w};
  float fa[8] = {f0.x, f0.y, f0.z, f0.w, f1.x, f1.y, f1.z, f1.w};
  short8 wv, mv;
#pragma unroll
  for (int j = 0; j < 8; ++j) {
    bool m = va[j] > 0.0f;
    wv[j] = (short)f2bf(m ? fa[j] : 0.0f);
    mv[j] = (short)(m ? 0x3F80 : 0x0000);  // bf16 1.0 / 0.0
  }
  *reinterpret_cast<short8*>(wb + idx) = wv;
  *reinterpret_cast<short8*>(mb + idx) = mv;
}

// ---------------------------------------------------------------------------
// Prep x: xb = bf16(x), ltb = bf16(max(log(tanh(100|x|)), -1e30))
// ---------------------------------------------------------------------------
__global__ __launch_bounds__(256) void prep_x(const float* __restrict__ x,
                                              unsigned short* __restrict__ xb,
                                              unsigned short* __restrict__ ltb) {
  int idx = (blockIdx.x * 256 + threadIdx.x) * 8;
  float4 x0 = *reinterpret_cast<const float4*>(x + idx);
  float4 x1 = *reinterpret_cast<const float4*>(x + idx + 4);
  float xa[8] = {x0.x, x0.y, x0.z, x0.w, x1.x, x1.y, x1.z, x1.w};
  short8 xv, lv;
#pragma unroll
  for (int j = 0; j < 8; ++j) {
    xv[j] = (short)f2bf(xa[j]);
    float l = fmaxf(logf(tanhf(100.0f * fabsf(xa[j]))), -1e30f);
    lv[j] = (short)f2bf(l);
  }
  *reinterpret_cast<short8*>(xb + idx) = xv;
  *reinterpret_cast<short8*>(ltb + idx) = lv;
}

// ---------------------------------------------------------------------------
// Dual MFMA GEMM. Tile 32(M) x 64(N) x 64(K-step); 4 waves (2M x 2N), each
// wave computes 16x32 via 1x2 fragments of 16x16, two accumulators each
// (dot with wb, slog with mb). Split-K partials to ws, or fused epilogue.
// ---------------------------------------------------------------------------
template <int SPLITK>
__global__ __launch_bounds__(256) void mfma_dual(
    const unsigned short* __restrict__ xb, const unsigned short* __restrict__ ltb,
    const unsigned short* __restrict__ wb, const unsigned short* __restrict__ mb,
    float* __restrict__ out, float* __restrict__ pdot,
    float* __restrict__ pslog) {
  constexpr int KC = I_ / SPLITK;
  const int on0 = blockIdx.x * 64;
  const int bm0 = blockIdx.y * 32;
  const int k0 = blockIdx.z * KC;

  // +8 elem (16B) row pad: 144B row stride -> balanced banks for b128 ops
  __shared__ short As[32][72];
  __shared__ short Ls[32][72];
  __shared__ short Ws[64][72];
  __shared__ short Ms[64][72];

  const int t = threadIdx.x;
  const int lane = t & 63;
  const int wid = t >> 6;
  const int wm = wid >> 1, wn = wid & 1;
  const int lr = lane & 15;
  const int lk = (lane >> 4) * 8;

  const int sr = t >> 3;          // staging row 0..31
  const int sc = (t & 7) * 8;     // staging col (elems)

  f32x4 z = {0.f, 0.f, 0.f, 0.f};
  f32x4 accd[2] = {z, z};
  f32x4 accs[2] = {z, z};

  for (int kt = 0; kt < KC; kt += 64) {
    const int gk = k0 + kt + sc;
    *reinterpret_cast<short8*>(&As[sr][sc]) =
        *reinterpret_cast<const short8*>(&xb[(size_t)(bm0 + sr) * I_ + gk]);
    *reinterpret_cast<short8*>(&Ls[sr][sc]) =
        *reinterpret_cast<const short8*>(&ltb[(size_t)(bm0 + sr) * I_ + gk]);
    *reinterpret_cast<short8*>(&Ws[sr][sc]) =
        *reinterpret_cast<const short8*>(&wb[(size_t)(on0 + sr) * I_ + gk]);
    *reinterpret_cast<short8*>(&Ws[32 + sr][sc]) =
        *reinterpret_cast<const short8*>(&wb[(size_t)(on0 + 32 + sr) * I_ + gk]);
    *reinterpret_cast<short8*>(&Ms[sr][sc]) =
        *reinterpret_cast<const short8*>(&mb[(size_t)(on0 + sr) * I_ + gk]);
    *reinterpret_cast<short8*>(&Ms[32 + sr][sc]) =
        *reinterpret_cast<const short8*>(&mb[(size_t)(on0 + 32 + sr) * I_ + gk]);
    __syncthreads();

#pragma unroll
    for (int ks = 0; ks < 2; ++ks) {
      const int kb = ks * 32 + lk;
      short8 af = *reinterpret_cast<const short8*>(&As[wm * 16 + lr][kb]);
      short8 lf = *reinterpret_cast<const short8*>(&Ls[wm * 16 + lr][kb]);
      short8 w0 = *reinterpret_cast<const short8*>(&Ws[wn * 32 + lr][kb]);
      short8 w1 = *reinterpret_cast<const short8*>(&Ws[wn * 32 + 16 + lr][kb]);
      short8 m0 = *reinterpret_cast<const short8*>(&Ms[wn * 32 + lr][kb]);
      short8 m1 = *reinterpret_cast<const short8*>(&Ms[wn * 32 + 16 + lr][kb]);
      accd[0] = __builtin_amdgcn_mfma_f32_16x16x32_bf16(af, w0, accd[0], 0, 0, 0);
      accd[1] = __builtin_amdgcn_mfma_f32_16x16x32_bf16(af, w1, accd[1], 0, 0, 0);
      accs[0] = __builtin_amdgcn_mfma_f32_16x16x32_bf16(lf, m0, accs[0], 0, 0, 0);
      accs[1] = __builtin_amdgcn_mfma_f32_16x16x32_bf16(lf, m1, accs[1], 0, 0, 0);
    }
    __syncthreads();
  }

  // C/D layout: col = lane&15, row = (lane>>4)*4 + reg   [m89-verified]
  const int orow = bm0 + wm * 16 + (lane >> 4) * 4;
  const int ocol = on0 + wn * 32 + lr;
  if constexpr (SPLITK == 1) {
#pragma unroll
    for (int n = 0; n < 2; ++n) {
#pragma unroll
      for (int r = 0; r < 4; ++r) {
        float d = expf(accs[n][r]);
        float y = fmaxf(accd[n][r] * d, 0.0f);
        size_t off = (size_t)(orow + r) * O_ + ocol + n * 16;
        out[off] = y;
        out[(size_t)B_ * O_ + off] = d;
      }
    }
  } else {
    const size_t base = (size_t)blockIdx.z * B_ * O_;
#pragma unroll
    for (int n = 0; n < 2; ++n) {
#pragma unroll
      for (int r = 0; r < 4; ++r) {
        size_t off = base + (size_t)(orow + r) * O_ + ocol + n * 16;
        pdot[off] = accd[n][r];
        pslog[off] = accs[n][r];
      }
    }
  }
}

// ---------------------------------------------------------------------------
// Split-K reduce + epilogue: delta = exp(sum slog), y = relu(sum dot * delta)
// ---------------------------------------------------------------------------
__global__ __launch_bounds__(256) void reduce_ep(const float* __restrict__ pdot,
                                                 const float* __restrict__ pslog,
                                                 float* __restrict__ out) {
  int idx = blockIdx.x * 256 + threadIdx.x;
  float d = 0.f, s = 0.f;
#pragma unroll
  for (int ks = 0; ks < NSPLIT; ++ks) {
    d += pdot[(size_t)ks * B_ * O_ + idx];
    s += pslog[(size_t)ks * B_ * O_ + idx];
  }
  float delta = expf(s);
  out[idx] = fmaxf(d * delta, 0.0f);
  out[(size_t)B_ * O_ + idx] = delta;
}

// ---------------------------------------------------------------------------
// fp32 fallback (no workspace): round-1 kernel, inline log-tanh, fused epilogue
// ---------------------------------------------------------------------------
__global__ __launch_bounds__(256) void dual_gemm_f32(
    const float* __restrict__ x, const float* __restrict__ vw,
    const float* __restrict__ fcw, float* __restrict__ out) {
  const int on0 = blockIdx.x * 64;
  const int bm0 = blockIdx.y * 64;
  __shared__ float xs[32][68];
  __shared__ float ls[32][68];
  __shared__ float wsm[32][68];
  __shared__ float msh[32][68];
  const int t = threadIdx.x;
  const int tx = t & 15, ty = t >> 4;
  const int m0 = ty * 4, n0 = tx * 4;
  float accd[4][4] = {{0.f}};
  float accs[4][4] = {{0.f}};
  for (int kt = 0; kt < I_; kt += 32) {
#pragma unroll
    for (int j = 0; j < 8; ++j) {
      int f = j * 256 + t;
      int m = f >> 5;
      int kk = f & 31;
      int gk = kt + kk;
      float xv = x[(size_t)(bm0 + m) * I_ + gk];
      xs[kk][m] = xv;
      ls[kk][m] = fmaxf(logf(tanhf(100.0f * fabsf(xv))), -1e30f);
      float vv = vw[(size_t)(on0 + m) * I_ + gk];
      float fv = fcw[(size_t)(on0 + m) * I_ + gk];
      float mk = vv > 0.0f ? 1.0f : 0.0f;
      wsm[kk][m] = fv * mk;
      msh[kk][m] = mk;
    }
    __syncthreads();
#pragma unroll
    for (int kk = 0; kk < 32; ++kk) {
      float4 xv = *reinterpret_cast<const float4*>(&xs[kk][m0]);
      float4 lv = *reinterpret_cast<const float4*>(&ls[kk][m0]);
      float4 wv = *reinterpret_cast<const float4*>(&wsm[kk][n0]);
      float4 mv = *reinterpret_cast<const float4*>(&msh[kk][n0]);
      float xa[4] = {xv.x, xv.y, xv.z, xv.w};
      float la[4] = {lv.x, lv.y, lv.z, lv.w};
      float wa[4] = {wv.x, wv.y, wv.z, wv.w};
      float ma[4] = {mv.x, mv.y, mv.z, mv.w};
#pragma unroll
      for (int i = 0; i < 4; ++i)
#pragma unroll
        for (int j = 0; j < 4; ++j) {
          accd[i][j] = fmaf(xa[i], wa[j], accd[i][j]);
          accs[i][j] = fmaf(la[i], ma[j], accs[i][j]);
        }
    }
    __syncthreads();
  }
#pragma unroll
  for (int i = 0; i < 4; ++i) {
    int row = bm0 + m0 + i;
#pragma unroll
    for (int j = 0; j < 4; ++j) {
      float delta = expf(accs[i][j]);
      out[(size_t)row * O_ + on0 + n0 + j] = fmaxf(accd[i][j] * delta, 0.0f);
      out[(size_t)B_ * O_ + (size_t)row * O_ + on0 + n0 + j] = delta;
    }
  }
}

extern "C" void kernel_launch(void* const* d_in, const int* in_sizes, int n_in,
                              void* d_out, int out_size, void* d_ws,
                              size_t ws_size, hipStream_t stream) {
  const float* x = (const float*)d_in[0];
  const float* vw = (const float*)d_in[1];
  const float* fcw = (const float*)d_in[2];
  float* out = (float*)d_out;

  const size_t xbB = (size_t)B_ * I_ * 2;      // 512 KB
  const size_t wbB = (size_t)O_ * I_ * 2;      // 2 MB
  const size_t bfB = 2 * xbB + 2 * wbB;        // 5 MB
  const size_t pB = (size_t)NSPLIT * B_ * O_ * 4;  // 4 MB each

  unsigned short* xb = (unsigned short*)d_ws;
  unsigned short* ltb = (unsigned short*)((char*)d_ws + xbB);
  unsigned short* wb = (unsigned short*)((char*)d_ws + 2 * xbB);
  unsigned short* mb = (unsigned short*)((char*)d_ws + 2 * xbB + wbB);
  float* pdot = (float*)((char*)d_ws + bfB);
  float* pslog = (float*)((char*)d_ws + bfB + pB);

  if (ws_size >= bfB + 2 * pB) {
    prep_w<<<(O_ * I_) / 2048, 256, 0, stream>>>(vw, fcw, wb, mb);
    prep_x<<<(B_ * I_) / 2048, 256, 0, stream>>>(x, xb, ltb);
    mfma_dual<NSPLIT><<<dim3(O_ / 64, B_ / 32, NSPLIT), 256, 0, stream>>>(
        xb, ltb, wb, mb, out, pdot, pslog);
    reduce_ep<<<(B_ * O_) / 256, 256, 0, stream>>>(pdot, pslog, out);
  } else if (ws_size >= bfB) {
    prep_w<<<(O_ * I_) / 2048, 256, 0, stream>>>(vw, fcw, wb, mb);
    prep_x<<<(B_ * I_) / 2048, 256, 0, stream>>>(x, xb, ltb);
    mfma_dual<1><<<dim3(O_ / 64, B_ / 32, 1), 256, 0, stream>>>(
        xb, ltb, wb, mb, out, nullptr, nullptr);
  } else {
    dual_gemm_f32<<<dim3(O_ / 64, B_ / 64, 1), 256, 0, stream>>>(x, vw, fcw, out);
  }
}

// Round 3
// 17.928 us; speedup vs baseline: 2.2556x; 1.3803x over previous
//
#include <hip/hip_runtime.h>
#include <cmath>

// Problem constants (fixed by the reference)
#define B_ 256
#define I_ 1024
#define O_ 1024

typedef __attribute__((ext_vector_type(8))) short short8;   // 8 bf16 = 4 VGPRs
typedef __attribute__((ext_vector_type(4))) float f32x4;

// float -> bf16 bits, round-to-nearest-even (inputs are finite)
__device__ inline unsigned short f2bf(float f) {
  union { float f; unsigned u; } c;
  c.f = f;
  unsigned u = c.u;
  return (unsigned short)((u + 0x7FFFu + ((u >> 16) & 1u)) >> 16);
}

#define WBLKS ((O_ * I_) / 2048)   // 512 blocks for weight prep
#define XBLKS ((B_ * I_) / 2048)   // 128 blocks for x prep

// ---------------------------------------------------------------------------
// Merged prep (one launch):
//   blocks [0, WBLKS):     wb = bf16(fc * (vw>0)), mb = bf16(vw>0)
//   blocks [WBLKS, +XBLKS): xb = bf16(x), ltb = bf16(max(log(tanh(100|x|)),-1e30))
// ---------------------------------------------------------------------------
__global__ __launch_bounds__(256) void prep_all(
    const float* __restrict__ x, const float* __restrict__ vw,
    const float* __restrict__ fcw, unsigned short* __restrict__ xb,
    unsigned short* __restrict__ ltb, unsigned short* __restrict__ wb,
    unsigned short* __restrict__ mb) {
  const int bid = blockIdx.x;
  if (bid < WBLKS) {
    int idx = (bid * 256 + threadIdx.x) * 8;
    float4 v0 = *reinterpret_cast<const float4*>(vw + idx);
    float4 v1 = *reinterpret_cast<const float4*>(vw + idx + 4);
    float4 f0 = *reinterpret_cast<const float4*>(fcw + idx);
    float4 f1 = *reinterpret_cast<const float4*>(fcw + idx + 4);
    float va[8] = {v0.x, v0.y, v0.z, v0.w, v1.x, v1.y, v1.z, v1.w};
    float fa[8] = {f0.x, f0.y, f0.z, f0.w, f1.x, f1.y, f1.z, f1.w};
    short8 wv, mv;
#pragma unroll
    for (int j = 0; j < 8; ++j) {
      bool m = va[j] > 0.0f;
      wv[j] = (short)f2bf(m ? fa[j] : 0.0f);
      mv[j] = (short)(m ? 0x3F80 : 0x0000);  // bf16 1.0 / 0.0
    }
    *reinterpret_cast<short8*>(wb + idx) = wv;
    *reinterpret_cast<short8*>(mb + idx) = mv;
  } else {
    int idx = ((bid - WBLKS) * 256 + threadIdx.x) * 8;
    float4 x0 = *reinterpret_cast<const float4*>(x + idx);
    float4 x1 = *reinterpret_cast<const float4*>(x + idx + 4);
    float xa[8] = {x0.x, x0.y, x0.z, x0.w, x1.x, x1.y, x1.z, x1.w};
    short8 xv, lv;
#pragma unroll
    for (int j = 0; j < 8; ++j) {
      xv[j] = (short)f2bf(xa[j]);
      float l = fmaxf(logf(tanhf(100.0f * fabsf(xa[j]))), -1e30f);
      lv[j] = (short)f2bf(l);
    }
    *reinterpret_cast<short8*>(xb + idx) = xv;
    *reinterpret_cast<short8*>(ltb + idx) = lv;
  }
}

// ---------------------------------------------------------------------------
// Fused dual MFMA GEMM, no split-K. Tile 32(M) x 32(N) x full K=1024.
// Grid (O/32, B/32) = (32, 8) = 256 blocks, 256 threads = 4 waves (2x2),
// each wave computes one 16x16 fragment of dot AND of slog.
// Register-prefetch (tile k+1 in regs) overlaps HBM/L2 latency with MFMA.
// Epilogue fused: delta = exp(slog), y = relu(dot * delta).
// ---------------------------------------------------------------------------
__global__ __launch_bounds__(256) void mfma_fused(
    const unsigned short* __restrict__ xb, const unsigned short* __restrict__ ltb,
    const unsigned short* __restrict__ wb, const unsigned short* __restrict__ mb,
    float* __restrict__ out) {
  const int on0 = blockIdx.x * 32;
  const int bm0 = blockIdx.y * 32;

  // 72-short rows = 144B = 9*16B: staging stores and fragment reads both
  // spread perfectly across the 8 LDS 4-bank groups (conflict-free).
  __shared__ short As[32][72];
  __shared__ short Ls[32][72];
  __shared__ short Ws[32][72];
  __shared__ short Ms[32][72];

  const int t = threadIdx.x;
  const int lane = t & 63;
  const int wid = t >> 6;
  const int wm = wid >> 1, wn = wid & 1;
  const int lr = lane & 15;
  const int lk = (lane >> 4) * 8;

  const int srow = t >> 3;         // staging row 0..31
  const int scol = (t & 7) * 8;    // staging col (elems)

  const size_t aoff = (size_t)(bm0 + srow) * I_ + scol;
  const size_t boff = (size_t)(on0 + srow) * I_ + scol;

  // prefetch tile 0
  short8 rx = *reinterpret_cast<const short8*>(xb + aoff);
  short8 rl = *reinterpret_cast<const short8*>(ltb + aoff);
  short8 rw = *reinterpret_cast<const short8*>(wb + boff);
  short8 rm = *reinterpret_cast<const short8*>(mb + boff);

  f32x4 accd = {0.f, 0.f, 0.f, 0.f};
  f32x4 accs = {0.f, 0.f, 0.f, 0.f};

  for (int kt = 0; kt < I_; kt += 64) {
    __syncthreads();  // previous iter's reads done before overwrite
    *reinterpret_cast<short8*>(&As[srow][scol]) = rx;
    *reinterpret_cast<short8*>(&Ls[srow][scol]) = rl;
    *reinterpret_cast<short8*>(&Ws[srow][scol]) = rw;
    *reinterpret_cast<short8*>(&Ms[srow][scol]) = rm;
    if (kt + 64 < I_) {  // issue next-tile loads; latency hides under MFMA
      rx = *reinterpret_cast<const short8*>(xb + aoff + kt + 64);
      rl = *reinterpret_cast<const short8*>(ltb + aoff + kt + 64);
      rw = *reinterpret_cast<const short8*>(wb + boff + kt + 64);
      rm = *reinterpret_cast<const short8*>(mb + boff + kt + 64);
    }
    __syncthreads();
#pragma unroll
    for (int ks = 0; ks < 2; ++ks) {
      const int kb = ks * 32 + lk;
      short8 af = *reinterpret_cast<const short8*>(&As[wm * 16 + lr][kb]);
      short8 lf = *reinterpret_cast<const short8*>(&Ls[wm * 16 + lr][kb]);
      short8 wf = *reinterpret_cast<const short8*>(&Ws[wn * 16 + lr][kb]);
      short8 mf = *reinterpret_cast<const short8*>(&Ms[wn * 16 + lr][kb]);
      accd = __builtin_amdgcn_mfma_f32_16x16x32_bf16(af, wf, accd, 0, 0, 0);
      accs = __builtin_amdgcn_mfma_f32_16x16x32_bf16(lf, mf, accs, 0, 0, 0);
    }
  }

  // C/D layout: col = lane&15, row = (lane>>4)*4 + reg   [m89-verified]
  const int orow = bm0 + wm * 16 + (lane >> 4) * 4;
  const int ocol = on0 + wn * 16 + lr;
#pragma unroll
  for (int r = 0; r < 4; ++r) {
    float d = expf(accs[r]);
    float y = fmaxf(accd[r] * d, 0.0f);
    size_t off = (size_t)(orow + r) * O_ + ocol;
    out[off] = y;
    out[(size_t)B_ * O_ + off] = d;
  }
}

// ---------------------------------------------------------------------------
// fp32 fallback (workspace too small): inline log-tanh, fused epilogue
// ---------------------------------------------------------------------------
__global__ __launch_bounds__(256) void dual_gemm_f32(
    const float* __restrict__ x, const float* __restrict__ vw,
    const float* __restrict__ fcw, float* __restrict__ out) {
  const int on0 = blockIdx.x * 64;
  const int bm0 = blockIdx.y * 64;
  __shared__ float xs[32][68];
  __shared__ float ls[32][68];
  __shared__ float wsm[32][68];
  __shared__ float msh[32][68];
  const int t = threadIdx.x;
  const int tx = t & 15, ty = t >> 4;
  const int m0 = ty * 4, n0 = tx * 4;
  float accd[4][4] = {{0.f}};
  float accs[4][4] = {{0.f}};
  for (int kt = 0; kt < I_; kt += 32) {
#pragma unroll
    for (int j = 0; j < 8; ++j) {
      int f = j * 256 + t;
      int m = f >> 5;
      int kk = f & 31;
      int gk = kt + kk;
      float xv = x[(size_t)(bm0 + m) * I_ + gk];
      xs[kk][m] = xv;
      ls[kk][m] = fmaxf(logf(tanhf(100.0f * fabsf(xv))), -1e30f);
      float vv = vw[(size_t)(on0 + m) * I_ + gk];
      float fv = fcw[(size_t)(on0 + m) * I_ + gk];
      float mk = vv > 0.0f ? 1.0f : 0.0f;
      wsm[kk][m] = fv * mk;
      msh[kk][m] = mk;
    }
    __syncthreads();
#pragma unroll
    for (int kk = 0; kk < 32; ++kk) {
      float4 xv = *reinterpret_cast<const float4*>(&xs[kk][m0]);
      float4 lv = *reinterpret_cast<const float4*>(&ls[kk][m0]);
      float4 wv = *reinterpret_cast<const float4*>(&wsm[kk][n0]);
      float4 mv = *reinterpret_cast<const float4*>(&msh[kk][n0]);
      float xa[4] = {xv.x, xv.y, xv.z, xv.w};
      float la[4] = {lv.x, lv.y, lv.z, lv.w};
      float wa[4] = {wv.x, wv.y, wv.z, wv.w};
      float ma[4] = {mv.x, mv.y, mv.z, mv.w};
#pragma unroll
      for (int i = 0; i < 4; ++i)
#pragma unroll
        for (int j = 0; j < 4; ++j) {
          accd[i][j] = fmaf(xa[i], wa[j], accd[i][j]);
          accs[i][j] = fmaf(la[i], ma[j], accs[i][j]);
        }
    }
    __syncthreads();
  }
#pragma unroll
  for (int i = 0; i < 4; ++i) {
    int row = bm0 + m0 + i;
#pragma unroll
    for (int j = 0; j < 4; ++j) {
      float delta = expf(accs[i][j]);
      out[(size_t)row * O_ + on0 + n0 + j] = fmaxf(accd[i][j] * delta, 0.0f);
      out[(size_t)B_ * O_ + (size_t)row * O_ + on0 + n0 + j] = delta;
    }
  }
}

extern "C" void kernel_launch(void* const* d_in, const int* in_sizes, int n_in,
                              void* d_out, int out_size, void* d_ws,
                              size_t ws_size, hipStream_t stream) {
  const float* x = (const float*)d_in[0];
  const float* vw = (const float*)d_in[1];
  const float* fcw = (const float*)d_in[2];
  float* out = (float*)d_out;

  const size_t xbB = (size_t)B_ * I_ * 2;  // 512 KB
  const size_t wbB = (size_t)O_ * I_ * 2;  // 2 MB
  const size_t bfB = 2 * xbB + 2 * wbB;    // 5 MB total

  unsigned short* xb = (unsigned short*)d_ws;
  unsigned short* ltb = (unsigned short*)((char*)d_ws + xbB);
  unsigned short* wb = (unsigned short*)((char*)d_ws + 2 * xbB);
  unsigned short* mb = (unsigned short*)((char*)d_ws + 2 * xbB + wbB);

  if (ws_size >= bfB) {
    prep_all<<<WBLKS + XBLKS, 256, 0, stream>>>(x, vw, fcw, xb, ltb, wb, mb);
    mfma_fused<<<dim3(O_ / 32, B_ / 32), 256, 0, stream>>>(xb, ltb, wb, mb, out);
  } else {
    dual_gemm_f32<<<dim3(O_ / 64, B_ / 64, 1), 256, 0, stream>>>(x, vw, fcw, out);
  }
}

// Round 4
// 16.778 us; speedup vs baseline: 2.4102x; 1.0686x over previous
//
#include <hip/hip_runtime.h>
#include <cmath>

// Problem constants (fixed by the reference)
#define B_ 256
#define I_ 1024
#define O_ 1024

typedef __attribute__((ext_vector_type(8))) short short8;   // 8 bf16 = 4 VGPRs
typedef __attribute__((ext_vector_type(4))) float f32x4;

// float -> bf16 bits, round-to-nearest-even (inputs are finite)
__device__ inline unsigned short f2bf(float f) {
  union { float f; unsigned u; } c;
  c.f = f;
  unsigned u = c.u;
  return (unsigned short)((u + 0x7FFFu + ((u >> 16) & 1u)) >> 16);
}

#define WBLKS ((O_ * I_) / 2048)   // 512 blocks for weight prep
#define XBLKS ((B_ * I_) / 2048)   // 128 blocks for x prep

// ---------------------------------------------------------------------------
// Merged prep (one launch):
//   blocks [0, WBLKS):     wb = bf16(fc * (vw>0)), mb = bf16(vw>0)
//   blocks [WBLKS, +XBLKS): xb = bf16(x), ltb = bf16(max(log(tanh(100|x|)),-1e30))
// ---------------------------------------------------------------------------
__global__ __launch_bounds__(256) void prep_all(
    const float* __restrict__ x, const float* __restrict__ vw,
    const float* __restrict__ fcw, unsigned short* __restrict__ xb,
    unsigned short* __restrict__ ltb, unsigned short* __restrict__ wb,
    unsigned short* __restrict__ mb) {
  const int bid = blockIdx.x;
  if (bid < WBLKS) {
    int idx = (bid * 256 + threadIdx.x) * 8;
    float4 v0 = *reinterpret_cast<const float4*>(vw + idx);
    float4 v1 = *reinterpret_cast<const float4*>(vw + idx + 4);
    float4 f0 = *reinterpret_cast<const float4*>(fcw + idx);
    float4 f1 = *reinterpret_cast<const float4*>(fcw + idx + 4);
    float va[8] = {v0.x, v0.y, v0.z, v0.w, v1.x, v1.y, v1.z, v1.w};
    float fa[8] = {f0.x, f0.y, f0.z, f0.w, f1.x, f1.y, f1.z, f1.w};
    short8 wv, mv;
#pragma unroll
    for (int j = 0; j < 8; ++j) {
      bool m = va[j] > 0.0f;
      wv[j] = (short)f2bf(m ? fa[j] : 0.0f);
      mv[j] = (short)(m ? 0x3F80 : 0x0000);  // bf16 1.0 / 0.0
    }
    *reinterpret_cast<short8*>(wb + idx) = wv;
    *reinterpret_cast<short8*>(mb + idx) = mv;
  } else {
    int idx = ((bid - WBLKS) * 256 + threadIdx.x) * 8;
    float4 x0 = *reinterpret_cast<const float4*>(x + idx);
    float4 x1 = *reinterpret_cast<const float4*>(x + idx + 4);
    float xa[8] = {x0.x, x0.y, x0.z, x0.w, x1.x, x1.y, x1.z, x1.w};
    short8 xv, lv;
#pragma unroll
    for (int j = 0; j < 8; ++j) {
      xv[j] = (short)f2bf(xa[j]);
      float l = fmaxf(logf(tanhf(100.0f * fabsf(xa[j]))), -1e30f);
      lv[j] = (short)f2bf(l);
    }
    *reinterpret_cast<short8*>(xb + idx) = xv;
    *reinterpret_cast<short8*>(ltb + idx) = lv;
  }
}

// ---------------------------------------------------------------------------
// Fused dual MFMA GEMM with INTRA-BLOCK split-K.
// Tile 32(M) x 32(N); 512 threads = 8 waves. Wave-group kg = wid>>2 handles
// K-half [kg*512, kg*512+512); within a group the 4 waves form a 2x2 grid of
// 16x16 fragments (dot and slog each). Each group has its own LDS buffers
// (register-prefetch double-staging, 8 K-iters). Cross-group combine is an
// 8KB LDS reduce (reusing the A-tile space) fused with the exp/relu epilogue.
// Grid (O/32, B/32) = 256 blocks -> 1 block/CU, 2 waves/SIMD.
// ---------------------------------------------------------------------------
__global__ __launch_bounds__(512) void mfma_fused2(
    const unsigned short* __restrict__ xb, const unsigned short* __restrict__ ltb,
    const unsigned short* __restrict__ wb, const unsigned short* __restrict__ mb,
    float* __restrict__ out) {
  const int on0 = blockIdx.x * 32;
  const int bm0 = blockIdx.y * 32;

  // 72-short rows = 144B = 9*16B: staging stores and fragment reads spread
  // across all 8 LDS bank-groups (conflict-free for b128 ops).
  __shared__ short As[2][32][72];
  __shared__ short Ls[2][32][72];
  __shared__ short Ws[2][32][72];
  __shared__ short Ms[2][32][72];

  const int t = threadIdx.x;
  const int lane = t & 63;
  const int wid = t >> 6;            // 0..7
  const int kg = wid >> 2;           // K-group (0: k<512, 1: k>=512)
  const int wm = (wid >> 1) & 1, wn = wid & 1;
  const int lr = lane & 15;
  const int lk = (lane >> 4) * 8;

  const int tl = t & 255;            // thread index within group
  const int srow = tl >> 3;          // staging row 0..31
  const int scol = (tl & 7) * 8;     // staging col (elems)

  const size_t aoff = (size_t)(bm0 + srow) * I_ + kg * 512 + scol;
  const size_t boff = (size_t)(on0 + srow) * I_ + kg * 512 + scol;

  // prefetch tile 0 of this group's K-half
  short8 rx = *reinterpret_cast<const short8*>(xb + aoff);
  short8 rl = *reinterpret_cast<const short8*>(ltb + aoff);
  short8 rw = *reinterpret_cast<const short8*>(wb + boff);
  short8 rm = *reinterpret_cast<const short8*>(mb + boff);

  f32x4 accd = {0.f, 0.f, 0.f, 0.f};
  f32x4 accs = {0.f, 0.f, 0.f, 0.f};

  for (int kt = 0; kt < 512; kt += 64) {
    __syncthreads();  // previous iter's LDS reads done before overwrite
    *reinterpret_cast<short8*>(&As[kg][srow][scol]) = rx;
    *reinterpret_cast<short8*>(&Ls[kg][srow][scol]) = rl;
    *reinterpret_cast<short8*>(&Ws[kg][srow][scol]) = rw;
    *reinterpret_cast<short8*>(&Ms[kg][srow][scol]) = rm;
    if (kt + 64 < 512) {  // issue next-tile loads; latency hides under MFMA
      rx = *reinterpret_cast<const short8*>(xb + aoff + kt + 64);
      rl = *reinterpret_cast<const short8*>(ltb + aoff + kt + 64);
      rw = *reinterpret_cast<const short8*>(wb + boff + kt + 64);
      rm = *reinterpret_cast<const short8*>(mb + boff + kt + 64);
    }
    __syncthreads();
#pragma unroll
    for (int ks = 0; ks < 2; ++ks) {
      const int kb = ks * 32 + lk;
      short8 af = *reinterpret_cast<const short8*>(&As[kg][wm * 16 + lr][kb]);
      short8 lf = *reinterpret_cast<const short8*>(&Ls[kg][wm * 16 + lr][kb]);
      short8 wf = *reinterpret_cast<const short8*>(&Ws[kg][wn * 16 + lr][kb]);
      short8 mf = *reinterpret_cast<const short8*>(&Ms[kg][wn * 16 + lr][kb]);
      accd = __builtin_amdgcn_mfma_f32_16x16x32_bf16(af, wf, accd, 0, 0, 0);
      accs = __builtin_amdgcn_mfma_f32_16x16x32_bf16(lf, mf, accs, 0, 0, 0);
    }
  }

  // Cross-group reduce (group 1 -> LDS, group 0 adds) + fused epilogue.
  __syncthreads();
  float* red = reinterpret_cast<float*>(&As[0][0][0]);  // 8KB needed, 9216B avail
  const int ridx = ((wid & 3) * 64 + lane) * 8;
  if (kg == 1) {
#pragma unroll
    for (int r = 0; r < 4; ++r) {
      red[ridx + r] = accd[r];
      red[ridx + 4 + r] = accs[r];
    }
  }
  __syncthreads();
  if (kg == 0) {
    // C/D layout: col = lane&15, row = (lane>>4)*4 + reg   [m89-verified]
    const int orow = bm0 + wm * 16 + (lane >> 4) * 4;
    const int ocol = on0 + wn * 16 + lr;
#pragma unroll
    for (int r = 0; r < 4; ++r) {
      float dsum = accd[r] + red[ridx + r];
      float ssum = accs[r] + red[ridx + 4 + r];
      float d = expf(ssum);
      float y = fmaxf(dsum * d, 0.0f);
      size_t off = (size_t)(orow + r) * O_ + ocol;
      out[off] = y;
      out[(size_t)B_ * O_ + off] = d;
    }
  }
}

// ---------------------------------------------------------------------------
// fp32 fallback (workspace too small): inline log-tanh, fused epilogue
// ---------------------------------------------------------------------------
__global__ __launch_bounds__(256) void dual_gemm_f32(
    const float* __restrict__ x, const float* __restrict__ vw,
    const float* __restrict__ fcw, float* __restrict__ out) {
  const int on0 = blockIdx.x * 64;
  const int bm0 = blockIdx.y * 64;
  __shared__ float xs[32][68];
  __shared__ float ls[32][68];
  __shared__ float wsm[32][68];
  __shared__ float msh[32][68];
  const int t = threadIdx.x;
  const int tx = t & 15, ty = t >> 4;
  const int m0 = ty * 4, n0 = tx * 4;
  float accd[4][4] = {{0.f}};
  float accs[4][4] = {{0.f}};
  for (int kt = 0; kt < I_; kt += 32) {
#pragma unroll
    for (int j = 0; j < 8; ++j) {
      int f = j * 256 + t;
      int m = f >> 5;
      int kk = f & 31;
      int gk = kt + kk;
      float xv = x[(size_t)(bm0 + m) * I_ + gk];
      xs[kk][m] = xv;
      ls[kk][m] = fmaxf(logf(tanhf(100.0f * fabsf(xv))), -1e30f);
      float vv = vw[(size_t)(on0 + m) * I_ + gk];
      float fv = fcw[(size_t)(on0 + m) * I_ + gk];
      float mk = vv > 0.0f ? 1.0f : 0.0f;
      wsm[kk][m] = fv * mk;
      msh[kk][m] = mk;
    }
    __syncthreads();
#pragma unroll
    for (int kk = 0; kk < 32; ++kk) {
      float4 xv = *reinterpret_cast<const float4*>(&xs[kk][m0]);
      float4 lv = *reinterpret_cast<const float4*>(&ls[kk][m0]);
      float4 wv = *reinterpret_cast<const float4*>(&wsm[kk][n0]);
      float4 mv = *reinterpret_cast<const float4*>(&msh[kk][n0]);
      float xa[4] = {xv.x, xv.y, xv.z, xv.w};
      float la[4] = {lv.x, lv.y, lv.z, lv.w};
      float wa[4] = {wv.x, wv.y, wv.z, wv.w};
      float ma[4] = {mv.x, mv.y, mv.z, mv.w};
#pragma unroll
      for (int i = 0; i < 4; ++i)
#pragma unroll
        for (int j = 0; j < 4; ++j) {
          accd[i][j] = fmaf(xa[i], wa[j], accd[i][j]);
          accs[i][j] = fmaf(la[i], ma[j], accs[i][j]);
        }
    }
    __syncthreads();
  }
#pragma unroll
  for (int i = 0; i < 4; ++i) {
    int row = bm0 + m0 + i;
#pragma unroll
    for (int j = 0; j < 4; ++j) {
      float delta = expf(accs[i][j]);
      out[(size_t)row * O_ + on0 + n0 + j] = fmaxf(accd[i][j] * delta, 0.0f);
      out[(size_t)B_ * O_ + (size_t)row * O_ + on0 + n0 + j] = delta;
    }
  }
}

extern "C" void kernel_launch(void* const* d_in, const int* in_sizes, int n_in,
                              void* d_out, int out_size, void* d_ws,
                              size_t ws_size, hipStream_t stream) {
  const float* x = (const float*)d_in[0];
  const float* vw = (const float*)d_in[1];
  const float* fcw = (const float*)d_in[2];
  float* out = (float*)d_out;

  const size_t xbB = (size_t)B_ * I_ * 2;  // 512 KB
  const size_t wbB = (size_t)O_ * I_ * 2;  // 2 MB
  const size_t bfB = 2 * xbB + 2 * wbB;    // 5 MB total

  unsigned short* xb = (unsigned short*)d_ws;
  unsigned short* ltb = (unsigned short*)((char*)d_ws + xbB);
  unsigned short* wb = (unsigned short*)((char*)d_ws + 2 * xbB);
  unsigned short* mb = (unsigned short*)((char*)d_ws + 2 * xbB + wbB);

  if (ws_size >= bfB) {
    prep_all<<<WBLKS + XBLKS, 256, 0, stream>>>(x, vw, fcw, xb, ltb, wb, mb);
    mfma_fused2<<<dim3(O_ / 32, B_ / 32), 512, 0, stream>>>(xb, ltb, wb, mb, out);
  } else {
    dual_gemm_f32<<<dim3(O_ / 64, B_ / 64, 1), 256, 0, stream>>>(x, vw, fcw, out);
  }
}